// Round 1
// baseline (148.283 us; speedup 1.0000x reference)
//
#include <hip/hip_runtime.h>
#include <hip/hip_bf16.h>

// Problem: NormalizedHistogram — x:[32,512,512,3] f32 in [0,1] -> [32,256,3] f32
// Each (image, channel) 256-bin histogram, normalized by its sum.
// Sum is always H*W = 262144 = 2^18 (every pixel is binned after clipping),
// so normalization is an exact *2^-18 scale.

#define NBINS      256
#define B_IMG      32
#define HW         (512 * 512)          // 262144 pixels per image
#define CH         3
#define ELEM_IMG   (HW * CH)            // 786432 floats per image
#define F4_IMG     (ELEM_IMG / 4)       // 196608 float4 per image
#define THREADS    256
#define BLK_IMG    32                   // blocks per image
#define THR_IMG    (THREADS * BLK_IMG)  // 8192 threads per image
#define F4_THR     (F4_IMG / THR_IMG)   // 24 float4 per thread
#define OUT_ELEMS  (B_IMG * NBINS * CH) // 24576

__global__ __launch_bounds__(THREADS) void zero_kernel(float* __restrict__ out) {
    int i = blockIdx.x * THREADS + threadIdx.x;
    if (i < OUT_ELEMS) out[i] = 0.0f;
}

__global__ __launch_bounds__(THREADS) void hist_kernel(const float4* __restrict__ x,
                                                       float* __restrict__ out) {
    __shared__ unsigned int hist[CH * NBINS]; // [c][bin], 3 KB

    const int tid = threadIdx.x;
    for (int j = tid; j < CH * NBINS; j += THREADS) hist[j] = 0u;
    __syncthreads();

    const int b = blockIdx.y;
    const float4* __restrict__ xb = x + (size_t)b * F4_IMG;
    const int t = blockIdx.x * THREADS + tid; // 0..THR_IMG-1

#pragma unroll 4
    for (int i = 0; i < F4_THR; ++i) {
        const int f = t + i * THR_IMG;     // float4 index within image (coalesced)
        const float4 v = xb[f];
        int c = (f * 4) % 3;               // channel of first element

        int b0 = min(NBINS - 1, max(0, (int)(v.x * 256.0f)));
        atomicAdd(&hist[c * NBINS + b0], 1u);
        c = (c == 2) ? 0 : c + 1;

        int b1 = min(NBINS - 1, max(0, (int)(v.y * 256.0f)));
        atomicAdd(&hist[c * NBINS + b1], 1u);
        c = (c == 2) ? 0 : c + 1;

        int b2 = min(NBINS - 1, max(0, (int)(v.z * 256.0f)));
        atomicAdd(&hist[c * NBINS + b2], 1u);
        c = (c == 2) ? 0 : c + 1;

        int b3 = min(NBINS - 1, max(0, (int)(v.w * 256.0f)));
        atomicAdd(&hist[c * NBINS + b3], 1u);
    }

    __syncthreads();

    // Flush block-local counts into out[b][bin][c] as float atomic adds.
    // All partial sums are integers < 2^24 -> exact & order-independent.
    float* __restrict__ ob = out + (size_t)b * (NBINS * CH);
    for (int j = tid; j < CH * NBINS; j += THREADS) {
        unsigned int cnt = hist[j];
        if (cnt) {
            int c   = j >> 8;    // j / 256
            int bin = j & 255;   // j % 256
            atomicAdd(&ob[bin * CH + c], (float)cnt);
        }
    }
}

__global__ __launch_bounds__(THREADS) void scale_kernel(float* __restrict__ out) {
    int i = blockIdx.x * THREADS + threadIdx.x;
    if (i < OUT_ELEMS) out[i] *= (1.0f / (float)HW); // *2^-18, exact
}

extern "C" void kernel_launch(void* const* d_in, const int* in_sizes, int n_in,
                              void* d_out, int out_size, void* d_ws, size_t ws_size,
                              hipStream_t stream) {
    const float4* x = (const float4*)d_in[0];
    float* out = (float*)d_out;

    zero_kernel<<<(OUT_ELEMS + THREADS - 1) / THREADS, THREADS, 0, stream>>>(out);

    dim3 grid(BLK_IMG, B_IMG); // 32 x 32 = 1024 blocks, 4 blocks/CU
    hist_kernel<<<grid, THREADS, 0, stream>>>(x, out);

    scale_kernel<<<(OUT_ELEMS + THREADS - 1) / THREADS, THREADS, 0, stream>>>(out);
}

// Round 3
// 146.899 us; speedup vs baseline: 1.0094x; 1.0094x over previous
//
#include <hip/hip_runtime.h>
#include <hip/hip_bf16.h>

// Problem: NormalizedHistogram — x:[32,512,512,3] f32 in [0,1] -> [32,256,3] f32
// Per-(image,channel) 256-bin histogram, normalized by its sum.
// Sum is always H*W = 262144 = 2^18 (every value lands in a bin after clip),
// so normalization is an exact *2^-18 scale, fused into the flush:
// each block's atomicAdd contributes cnt*2^-18 = k*2^-18 (k integer < 2^24),
// so every intermediate float sum is exact and order-independent.

#define NBINS      256
#define B_IMG      32
#define HW         (512 * 512)          // 262144 pixels per image
#define CH         3
#define ELEM_IMG   (HW * CH)            // 786432 floats per image
#define F4_IMG     (ELEM_IMG / 4)       // 196608 float4 per image
#define THREADS    256
#define BLK_IMG    64                   // blocks per image (2048 total, 8 wg/CU)
#define THR_IMG    (THREADS * BLK_IMG)  // 16384 threads per image
#define F4_THR     (F4_IMG / THR_IMG)   // 12 float4 per thread
#define OUT_ELEMS  (B_IMG * NBINS * CH) // 24576

typedef float floatx4 __attribute__((ext_vector_type(4))); // native vec for nontemporal builtin

__global__ __launch_bounds__(THREADS) void zero_kernel(float* __restrict__ out) {
    int i = blockIdx.x * THREADS + threadIdx.x;
    if (i < OUT_ELEMS) out[i] = 0.0f;
}

__global__ __launch_bounds__(THREADS) void hist_kernel(const floatx4* __restrict__ x,
                                                       float* __restrict__ out) {
    __shared__ unsigned int hist[CH * NBINS]; // [c][bin], 3 KB

    const int tid = threadIdx.x;
    for (int j = tid; j < CH * NBINS; j += THREADS) hist[j] = 0u;
    __syncthreads();

    const int b = blockIdx.y;
    const floatx4* __restrict__ xb = x + (size_t)b * F4_IMG;
    const int t = blockIdx.x * THREADS + tid; // 0..THR_IMG-1

#pragma unroll
    for (int i = 0; i < F4_THR; ++i) {
        const int f = t + i * THR_IMG;     // float4 index within image (coalesced)
        const floatx4 v = __builtin_nontemporal_load(&xb[f]);
        int c = (f * 4) % 3;               // channel of first element

        int b0 = min(NBINS - 1, max(0, (int)(v.x * 256.0f)));
        atomicAdd(&hist[c * NBINS + b0], 1u);
        c = (c == 2) ? 0 : c + 1;

        int b1 = min(NBINS - 1, max(0, (int)(v.y * 256.0f)));
        atomicAdd(&hist[c * NBINS + b1], 1u);
        c = (c == 2) ? 0 : c + 1;

        int b2 = min(NBINS - 1, max(0, (int)(v.z * 256.0f)));
        atomicAdd(&hist[c * NBINS + b2], 1u);
        c = (c == 2) ? 0 : c + 1;

        int b3 = min(NBINS - 1, max(0, (int)(v.w * 256.0f)));
        atomicAdd(&hist[c * NBINS + b3], 1u);
    }

    __syncthreads();

    // Flush block-local counts into out[b][bin][c], pre-scaled by 2^-18.
    // cnt*2^-18 is exact; all partial sums are k*2^-18, k<2^24 -> exact.
    float* __restrict__ ob = out + (size_t)b * (NBINS * CH);
    for (int j = tid; j < CH * NBINS; j += THREADS) {
        unsigned int cnt = hist[j];
        if (cnt) {
            int c   = j >> 8;    // j / 256
            int bin = j & 255;   // j % 256
            atomicAdd(&ob[bin * CH + c], (float)cnt * (1.0f / (float)HW));
        }
    }
}

extern "C" void kernel_launch(void* const* d_in, const int* in_sizes, int n_in,
                              void* d_out, int out_size, void* d_ws, size_t ws_size,
                              hipStream_t stream) {
    const floatx4* x = (const floatx4*)d_in[0];
    float* out = (float*)d_out;

    zero_kernel<<<(OUT_ELEMS + THREADS - 1) / THREADS, THREADS, 0, stream>>>(out);

    dim3 grid(BLK_IMG, B_IMG); // 64 x 32 = 2048 blocks, 8 wg/CU
    hist_kernel<<<grid, THREADS, 0, stream>>>(x, out);
}